// Round 5
// baseline (317.009 us; speedup 1.0000x reference)
//
#include <hip/hip_runtime.h>
#include <hip/hip_bf16.h>

// ---------------------------------------------------------------------------
// SelfAttentionHybrid: single-head attention, B=4 S=2048 E=1024, fp32 in/out.
// R5 changes vs R4:
//  (1) parity-split LDS swizzle: slot(kc,r) = 4*(kc&1) + (((kc>>1)+r)&3).
//      kc parity == lane-half of the MFMA fragment read -> the two kc values
//      read in one step occupy DISJOINT bank halves (R2/R4 full-range
//      swizzles both measured exactly +4cy/ds_read_b128; parity mixing is
//      the suspected mechanism).
//  (2) L2 supertile swizzle: remap (bx,by) -> 8-row supertiles, column-major
//      inside, to cut B-matrix refetch (scores FETCH 139MB vs 32MB ideal).
//  (3) all fp32->bf16 casts fused into ONE dispatch (7 dispatches total).
// ---------------------------------------------------------------------------

typedef __bf16 bf16_t;
typedef __bf16 bf16x8 __attribute__((ext_vector_type(8)));
typedef __bf16 bf16x4 __attribute__((ext_vector_type(4)));
typedef float  f32x16 __attribute__((ext_vector_type(16)));

__device__ __forceinline__ void async_copy16(const void* g, void* l) {
  __builtin_amdgcn_global_load_lds(
      (const __attribute__((address_space(1))) void*)g,
      (__attribute__((address_space(3))) void*)l, 16, 0, 0);
}

__device__ __forceinline__ void store_out(float* p, float v)  { *p = v; }
__device__ __forceinline__ void store_out(bf16_t* p, float v) { *p = (bf16_t)v; }

#define BM 128
#define BN 128
#define BKT 64

// ---------------------------------------------------------------------------
// C[M,N] = A[M,K](lda) x B[N,K](ldb)^T * scale + bias, bf16 in, fp32 acc.
// 256 thr = 4 waves (2x2); wave tile 64x64 = 2x2 of 32x32x16 MFMA.
// LDS: rows of 8 16B-chunks; slot (r, cc) holds global chunk
//   gcc = (((cc&3) - r) & 3)*2 + (cc>>2)   [inverse of slot(kc,r)]
// Read of chunk kc (= 2s + h, h = lane>>5) for row r:
//   slot = 4*h + ((s + r) & 3)
// Requires gridDim.y % 8 == 0 (all our launches satisfy this).
// NBIAS: 0 = none, 1 = bias b0[N], 3 = concat b0|b1|b2 (1024 each).
// ---------------------------------------------------------------------------
template <typename OutT, int NBIAS>
__global__ __launch_bounds__(256) void gemm_bt(
    const bf16_t* __restrict__ A, const bf16_t* __restrict__ B,
    OutT* __restrict__ C,
    const float* __restrict__ b0, const float* __restrict__ b1,
    const float* __restrict__ b2,
    int M, int N, int K, int lda, int ldb, int ldc, float scale,
    long long strideA, long long strideB, long long strideC) {
  const int z = blockIdx.z;
  A += (long long)z * strideA;
  B += (long long)z * strideB;
  C += (long long)z * strideC;

  // L2 supertile remap: 8 y-tiles per supertile, y-fastest inside.
  int bx = blockIdx.x, by = blockIdx.y;
  {
    const int GX  = gridDim.x;
    const int id  = by * GX + bx;
    const int per = GX * 8;
    const int grp = id / per;
    const int rem = id - grp * per;
    by = grp * 8 + (rem & 7);
    bx = rem >> 3;
  }

  __shared__ __align__(16) bf16_t As[BM * BKT];  // 16 KB
  __shared__ __align__(16) bf16_t Bs[BN * BKT];  // 16 KB

  const int t    = threadIdx.x;
  const int lane = t & 63;
  const int w    = t >> 6;
  const int wm   = w & 1;
  const int wn   = w >> 1;
  const int tileM = by * BM;
  const int tileN = bx * BN;

  f32x16 acc[2][2] = {};

  for (int k0 = 0; k0 < K; k0 += BKT) {
    // stage 128 rows x 64 bf16 per matrix; 16B chunks, parity-split swizzle
#pragma unroll
    for (int i = 0; i < 4; ++i) {
      const int c   = t + 256 * i;
      const int row = c >> 3;
      const int cc  = c & 7;
      const int gcc = ((((cc & 3) - row) & 3) << 1) | (cc >> 2);
      const int ldsbase = ((t & ~63) + 256 * i) * 8;  // wave-uniform base (elems)
      async_copy16(A + (long long)(tileM + row) * lda + k0 + gcc * 8, &As[ldsbase]);
      async_copy16(B + (long long)(tileN + row) * ldb + k0 + gcc * 8, &Bs[ldsbase]);
    }
    __syncthreads();

#pragma unroll
    for (int s = 0; s < 4; ++s) {        // k-step of 16; kc = 2s + (lane>>5)
      const int h = lane >> 5;
      bf16x8 af[2], bfr[2];
#pragma unroll
      for (int ti = 0; ti < 2; ++ti) {
        const int row = wm * 64 + ti * 32 + (lane & 31);
        const int slot = 4 * h + ((s + row) & 3);
        af[ti] = *(const bf16x8*)&As[row * BKT + slot * 8];
      }
#pragma unroll
      for (int tj = 0; tj < 2; ++tj) {
        const int row = wn * 64 + tj * 32 + (lane & 31);
        const int slot = 4 * h + ((s + row) & 3);
        bfr[tj] = *(const bf16x8*)&Bs[row * BKT + slot * 8];
      }
#pragma unroll
      for (int ti = 0; ti < 2; ++ti)
#pragma unroll
        for (int tj = 0; tj < 2; ++tj)
          acc[ti][tj] = __builtin_amdgcn_mfma_f32_32x32x16_bf16(
              af[ti], bfr[tj], acc[ti][tj], 0, 0, 0);
    }
    __syncthreads();
  }

  // epilogue: 32x32 C map: col = lane&31, row = (r&3) + 8*(r>>2) + 4*(lane>>5)
#pragma unroll
  for (int tj = 0; tj < 2; ++tj) {
    const int col = tileN + wn * 64 + tj * 32 + (lane & 31);
    float bv = 0.f;
    if (NBIAS == 1) bv = b0[col];
    if (NBIAS == 3) {
      const float* bp = col < 1024 ? b0 : (col < 2048 ? b1 : b2);
      bv = bp[col & 1023];
    }
#pragma unroll
    for (int ti = 0; ti < 2; ++ti) {
      const int rowb = tileM + wm * 64 + ti * 32 + 4 * (lane >> 5);
#pragma unroll
      for (int r = 0; r < 16; ++r) {
        const int row = rowb + (r & 3) + 8 * (r >> 2);
        store_out(&C[(long long)row * ldc + col], acc[ti][tj][r] * scale + bv);
      }
    }
  }
}

// ---------------------------------------------------------------------------
// fused cast: all 4 weights + x in one dispatch (flat grid, region decode).
// n4w = 2^18 (per-weight float4 count), n4x = 2^21. Grid = (4*n4w+n4x)/256.
// ---------------------------------------------------------------------------
__global__ __launch_bounds__(256) void cast_all(
    const float4* __restrict__ w0, const float4* __restrict__ w1,
    const float4* __restrict__ w2, const float4* __restrict__ w3,
    const float4* __restrict__ x,
    bf16x4* __restrict__ wdst, bf16x4* __restrict__ xdst) {
  const int N4W = 1 << 18;  // 1024*1024/4
  const int id = blockIdx.x * 256 + threadIdx.x;
  const float4* src;
  bf16x4* dst;
  if (id < 4 * N4W) {
    const int z = id >> 18;
    src = (z == 0 ? w0 : z == 1 ? w1 : z == 2 ? w2 : w3) + (id & (N4W - 1));
    dst = wdst + id;
  } else {
    const int i = id - 4 * N4W;
    src = x + i;
    dst = xdst + i;
  }
  const float4 v = *src;
  bf16x4 o;
  o[0] = (bf16_t)v.x; o[1] = (bf16_t)v.y; o[2] = (bf16_t)v.z; o[3] = (bf16_t)v.w;
  *dst = o;
}

// ---------------------------------------------------------------------------
// bf16 transpose [R,C](ldin) -> [C,R], batched via blockIdx.z
// ---------------------------------------------------------------------------
__global__ __launch_bounds__(256) void transpose_bf16(
    const bf16_t* __restrict__ in, bf16_t* __restrict__ out, int R, int C,
    int ldin, long long sIn, long long sOut) {
  in  += (long long)blockIdx.z * sIn;
  out += (long long)blockIdx.z * sOut;
  __shared__ bf16_t tile[32][33];
  const int tx = threadIdx.x, ty = threadIdx.y;
  const int x = blockIdx.x * 32 + tx;
  const int y0 = blockIdx.y * 32;
#pragma unroll
  for (int j = 0; j < 32; j += 8)
    tile[ty + j][tx] = in[(long long)(y0 + ty + j) * ldin + x];
  __syncthreads();
  const int x2 = y0 + tx;
  const int y2 = blockIdx.x * 32;
#pragma unroll
  for (int j = 0; j < 32; j += 8)
    out[(long long)(y2 + ty + j) * R + x2] = tile[tx][ty + j];
}

// ---------------------------------------------------------------------------
// row softmax: 2048-wide rows, 256 threads x 8 elems
// ---------------------------------------------------------------------------
__global__ __launch_bounds__(256) void softmax_rows(
    const bf16_t* __restrict__ S, bf16_t* __restrict__ P, int cols) {
  const long long row = blockIdx.x;
  const bf16x8* inp = (const bf16x8*)(S + row * cols);
  bf16x8* outp      = (bf16x8*)(P + row * cols);
  const int t = threadIdx.x;
  const int w = t >> 6, lane = t & 63;

  const bf16x8 v = inp[t];
  float f[8];
#pragma unroll
  for (int j = 0; j < 8; ++j) f[j] = (float)v[j];

  float m = f[0];
#pragma unroll
  for (int j = 1; j < 8; ++j) m = fmaxf(m, f[j]);
#pragma unroll
  for (int off = 32; off > 0; off >>= 1) m = fmaxf(m, __shfl_xor(m, off));

  __shared__ float red[8];
  if (lane == 0) red[w] = m;
  __syncthreads();
  m = fmaxf(fmaxf(red[0], red[1]), fmaxf(red[2], red[3]));

  float e[8], sum = 0.f;
#pragma unroll
  for (int j = 0; j < 8; ++j) { e[j] = __expf(f[j] - m); sum += e[j]; }
#pragma unroll
  for (int off = 32; off > 0; off >>= 1) sum += __shfl_xor(sum, off);
  if (lane == 0) red[4 + w] = sum;
  __syncthreads();
  sum = red[4] + red[5] + red[6] + red[7];

  const float inv = 1.f / sum;
  bf16x8 o;
#pragma unroll
  for (int j = 0; j < 8; ++j) o[j] = (bf16_t)(e[j] * inv);
  outp[t] = o;
}

// ---------------------------------------------------------------------------
extern "C" void kernel_launch(void* const* d_in, const int* in_sizes, int n_in,
                              void* d_out, int out_size, void* d_ws, size_t ws_size,
                              hipStream_t stream) {
  const int E = 1024, S = 2048, B = 4;
  const int BS = B * S;  // 8192

  const float* x  = (const float*)d_in[0];
  const float* Wq = (const float*)d_in[1];
  const float* bq = (const float*)d_in[2];
  const float* Wk = (const float*)d_in[3];
  const float* bk = (const float*)d_in[4];
  const float* Wv = (const float*)d_in[5];
  const float* bv = (const float*)d_in[6];
  const float* Wo = (const float*)d_in[7];
  const float* bo = (const float*)d_in[8];
  float* out = (float*)d_out;

  char* w = (char*)d_ws;
  const size_t MB = 1ull << 20;
  bf16_t* Wqkvb = (bf16_t*)(w + 0 * MB);          // 6 MB  [3072,1024]
  bf16_t* Wob   = Wqkvb + 3 * E * E;              // 2 MB
  bf16_t* xb    = (bf16_t*)(w + 8 * MB);          // 16 MB [8192,1024]
  bf16_t* QKVb  = (bf16_t*)(w + 24 * MB);         // 48 MB [8192,3072]
  bf16_t* VTb   = (bf16_t*)(w + 72 * MB);         // 16 MB [B][1024,2048]
  bf16_t* Sb    = (bf16_t*)(w + 88 * MB);         // 32 MB scores
  bf16_t* Pb    = (bf16_t*)(w + 8 * MB);          // 32 MB (xb + QKV[0:16MB] dead)
  bf16_t* Ob    = (bf16_t*)(w + 40 * MB);         // 16 MB (QKV[16:32MB] dead)

  // ---- all casts in one dispatch
  {
    const int totalBlocks = ((4 << 18) + (1 << 21)) / 256;  // 12288
    cast_all<<<totalBlocks, 256, 0, stream>>>(
        (const float4*)Wq, (const float4*)Wk, (const float4*)Wv,
        (const float4*)Wo, (const float4*)x, (bf16x4*)Wqkvb, (bf16x4*)xb);
  }

  // ---- fused QKV projection: [8192,3072] = xb . Wqkv^T + (bq|bk|bv)
  gemm_bt<bf16_t, 3><<<dim3(3 * E / BN, BS / BM, 1), 256, 0, stream>>>(
      xb, Wqkvb, QKVb, bq, bk, bv,
      BS, 3 * E, E, E, E, 3 * E, 1.f, 0, 0, 0);

  // ---- V^T per batch: [2048,1024](ld 3072) -> [1024,2048]
  transpose_bf16<<<dim3(E / 32, S / 32, B), dim3(32, 8), 0, stream>>>(
      QKVb + 2 * E, VTb, S, E, 3 * E, (long long)S * 3 * E, (long long)E * S);

  // ---- scores = Q . K^T * E^-0.5 per batch
  gemm_bt<bf16_t, 0><<<dim3(S / BN, S / BM, B), 256, 0, stream>>>(
      QKVb, QKVb + E, Sb, nullptr, nullptr, nullptr,
      S, S, E, 3 * E, 3 * E, S, 0.03125f,
      (long long)S * 3 * E, (long long)S * 3 * E, (long long)S * S);

  // ---- softmax
  softmax_rows<<<BS, 256, 0, stream>>>(Sb, Pb, S);

  // ---- O = P . (V^T)^T per batch
  gemm_bt<bf16_t, 0><<<dim3(E / BN, S / BM, B), 256, 0, stream>>>(
      Pb, VTb, Ob, nullptr, nullptr, nullptr,
      S, E, S, S, S, E, 1.f,
      (long long)S * S, (long long)E * S, (long long)S * E);

  // ---- y = O . Wo^T + bo
  gemm_bt<float, 1><<<dim3(E / BN, BS / BM, 1), 256, 0, stream>>>(
      Ob, Wob, out, bo, nullptr, nullptr,
      BS, E, E, E, E, E, 1.f, 0, 0, 0);
}

// Round 6
// 292.245 us; speedup vs baseline: 1.0847x; 1.0847x over previous
//
#include <hip/hip_runtime.h>
#include <hip/hip_bf16.h>

// ---------------------------------------------------------------------------
// SelfAttentionHybrid: single-head attention, B=4 S=2048 E=1024, fp32 in/out.
// R6 = R2 structure + XOR staging swizzle, with the MFMA K-order changed:
// step s consumes k-chunks {s, s+4} (kc = s + 4*lane_half) instead of
// {2s, 2s+1}. With slot = kc ^ (row&7), the low/high lane halves then hit
// DISJOINT slot sets (differ by ^4) -> no cross-half bank collisions (the
// mechanism behind the exact 4.0 extra cy/ds_read_b128 in R2/R4).
// Legal: each MFMA still pairs A,B at identical global k; union over s
// covers k 0..63 exactly once (re-permuted contraction order).
// Keeps R5's L2 supertile remap (FETCH 71.7->58 MB) and single fused cast.
// ---------------------------------------------------------------------------

typedef __bf16 bf16_t;
typedef __bf16 bf16x8 __attribute__((ext_vector_type(8)));
typedef __bf16 bf16x4 __attribute__((ext_vector_type(4)));
typedef float  f32x16 __attribute__((ext_vector_type(16)));

__device__ __forceinline__ void async_copy16(const void* g, void* l) {
  __builtin_amdgcn_global_load_lds(
      (const __attribute__((address_space(1))) void*)g,
      (__attribute__((address_space(3))) void*)l, 16, 0, 0);
}

__device__ __forceinline__ void store_out(float* p, float v)  { *p = v; }
__device__ __forceinline__ void store_out(bf16_t* p, float v) { *p = (bf16_t)v; }

#define BM 128
#define BN 128
#define BKT 64

// ---------------------------------------------------------------------------
// C[M,N] = A[M,K](lda) x B[N,K](ldb)^T * scale + bias, bf16 in, fp32 acc.
// 256 thr = 4 waves (2x2); wave tile 64x64 = 2x2 of 32x32x16 MFMA.
// LDS: row-major rows of 8 16B-chunks; slot (r, cc) holds chunk cc^(r&7).
// Read step s, half h=lane>>5: kc = s + 4h, slot = kc ^ (r&7).
//   Low half slots {s^r}, high half {(s+4)^r} = low ^ 4 -> disjoint halves.
// NBIAS: 0 = none, 1 = bias b0[N], 3 = concat b0|b1|b2 (1024 each).
// Requires gridDim.y % 8 == 0 (all launches satisfy).
// ---------------------------------------------------------------------------
template <typename OutT, int NBIAS>
__global__ __launch_bounds__(256) void gemm_bt(
    const bf16_t* __restrict__ A, const bf16_t* __restrict__ B,
    OutT* __restrict__ C,
    const float* __restrict__ b0, const float* __restrict__ b1,
    const float* __restrict__ b2,
    int M, int N, int K, int lda, int ldb, int ldc, float scale,
    long long strideA, long long strideB, long long strideC) {
  const int z = blockIdx.z;
  A += (long long)z * strideA;
  B += (long long)z * strideB;
  C += (long long)z * strideC;

  // L2 supertile remap: 8 y-tiles per supertile, y-fastest inside.
  int bx = blockIdx.x, by = blockIdx.y;
  {
    const int GX  = gridDim.x;
    const int id  = by * GX + bx;
    const int per = GX * 8;
    const int grp = id / per;
    const int rem = id - grp * per;
    by = grp * 8 + (rem & 7);
    bx = rem >> 3;
  }

  __shared__ __align__(16) bf16_t As[BM * BKT];  // 16 KB
  __shared__ __align__(16) bf16_t Bs[BN * BKT];  // 16 KB

  const int t    = threadIdx.x;
  const int lane = t & 63;
  const int w    = t >> 6;
  const int wm   = w & 1;
  const int wn   = w >> 1;
  const int tileM = by * BM;
  const int tileN = bx * BN;

  f32x16 acc[2][2] = {};

  for (int k0 = 0; k0 < K; k0 += BKT) {
    // stage 128 rows x 64 bf16 per matrix; 16B chunks, XOR swizzle
#pragma unroll
    for (int i = 0; i < 4; ++i) {
      const int c   = t + 256 * i;
      const int row = c >> 3;
      const int cc  = c & 7;
      const int gcc = cc ^ (row & 7);
      const int ldsbase = ((t & ~63) + 256 * i) * 8;  // wave-uniform base (elems)
      async_copy16(A + (long long)(tileM + row) * lda + k0 + gcc * 8, &As[ldsbase]);
      async_copy16(B + (long long)(tileN + row) * ldb + k0 + gcc * 8, &Bs[ldsbase]);
    }
    __syncthreads();

#pragma unroll
    for (int s = 0; s < 4; ++s) {        // step s consumes chunks {s, s+4}
      const int kc = s + 4 * (lane >> 5);
      bf16x8 af[2], bfr[2];
#pragma unroll
      for (int ti = 0; ti < 2; ++ti) {
        const int row = wm * 64 + ti * 32 + (lane & 31);
        af[ti] = *(const bf16x8*)&As[row * BKT + ((kc ^ (row & 7)) * 8)];
      }
#pragma unroll
      for (int tj = 0; tj < 2; ++tj) {
        const int row = wn * 64 + tj * 32 + (lane & 31);
        bfr[tj] = *(const bf16x8*)&Bs[row * BKT + ((kc ^ (row & 7)) * 8)];
      }
#pragma unroll
      for (int ti = 0; ti < 2; ++ti)
#pragma unroll
        for (int tj = 0; tj < 2; ++tj)
          acc[ti][tj] = __builtin_amdgcn_mfma_f32_32x32x16_bf16(
              af[ti], bfr[tj], acc[ti][tj], 0, 0, 0);
    }
    __syncthreads();
  }

  // epilogue: 32x32 C map: col = lane&31, row = (r&3) + 8*(r>>2) + 4*(lane>>5)
#pragma unroll
  for (int tj = 0; tj < 2; ++tj) {
    const int col = tileN + wn * 64 + tj * 32 + (lane & 31);
    float bv = 0.f;
    if (NBIAS == 1) bv = b0[col];
    if (NBIAS == 3) {
      const float* bp = col < 1024 ? b0 : (col < 2048 ? b1 : b2);
      bv = bp[col & 1023];
    }
#pragma unroll
    for (int ti = 0; ti < 2; ++ti) {
      const int rowb = tileM + wm * 64 + ti * 32 + 4 * (lane >> 5);
#pragma unroll
      for (int r = 0; r < 16; ++r) {
        const int row = rowb + (r & 3) + 8 * (r >> 2);
        store_out(&C[(long long)row * ldc + col], acc[ti][tj][r] * scale + bv);
      }
    }
  }
}

// ---------------------------------------------------------------------------
// fused cast: all 4 weights + x in one dispatch (flat grid, region decode).
// ---------------------------------------------------------------------------
__global__ __launch_bounds__(256) void cast_all(
    const float4* __restrict__ w0, const float4* __restrict__ w1,
    const float4* __restrict__ w2, const float4* __restrict__ w3,
    const float4* __restrict__ x,
    bf16x4* __restrict__ wdst, bf16x4* __restrict__ xdst) {
  const int N4W = 1 << 18;  // 1024*1024/4
  const int id = blockIdx.x * 256 + threadIdx.x;
  const float4* src;
  bf16x4* dst;
  if (id < 4 * N4W) {
    const int z = id >> 18;
    src = (z == 0 ? w0 : z == 1 ? w1 : z == 2 ? w2 : w3) + (id & (N4W - 1));
    dst = wdst + id;
  } else {
    const int i = id - 4 * N4W;
    src = x + i;
    dst = xdst + i;
  }
  const float4 v = *src;
  bf16x4 o;
  o[0] = (bf16_t)v.x; o[1] = (bf16_t)v.y; o[2] = (bf16_t)v.z; o[3] = (bf16_t)v.w;
  *dst = o;
}

// ---------------------------------------------------------------------------
// bf16 transpose [R,C](ldin) -> [C,R], batched via blockIdx.z
// ---------------------------------------------------------------------------
__global__ __launch_bounds__(256) void transpose_bf16(
    const bf16_t* __restrict__ in, bf16_t* __restrict__ out, int R, int C,
    int ldin, long long sIn, long long sOut) {
  in  += (long long)blockIdx.z * sIn;
  out += (long long)blockIdx.z * sOut;
  __shared__ bf16_t tile[32][33];
  const int tx = threadIdx.x, ty = threadIdx.y;
  const int x = blockIdx.x * 32 + tx;
  const int y0 = blockIdx.y * 32;
#pragma unroll
  for (int j = 0; j < 32; j += 8)
    tile[ty + j][tx] = in[(long long)(y0 + ty + j) * ldin + x];
  __syncthreads();
  const int x2 = y0 + tx;
  const int y2 = blockIdx.x * 32;
#pragma unroll
  for (int j = 0; j < 32; j += 8)
    out[(long long)(y2 + ty + j) * R + x2] = tile[tx][ty + j];
}

// ---------------------------------------------------------------------------
// row softmax: 2048-wide rows, 256 threads x 8 elems
// ---------------------------------------------------------------------------
__global__ __launch_bounds__(256) void softmax_rows(
    const bf16_t* __restrict__ S, bf16_t* __restrict__ P, int cols) {
  const long long row = blockIdx.x;
  const bf16x8* inp = (const bf16x8*)(S + row * cols);
  bf16x8* outp      = (bf16x8*)(P + row * cols);
  const int t = threadIdx.x;
  const int w = t >> 6, lane = t & 63;

  const bf16x8 v = inp[t];
  float f[8];
#pragma unroll
  for (int j = 0; j < 8; ++j) f[j] = (float)v[j];

  float m = f[0];
#pragma unroll
  for (int j = 1; j < 8; ++j) m = fmaxf(m, f[j]);
#pragma unroll
  for (int off = 32; off > 0; off >>= 1) m = fmaxf(m, __shfl_xor(m, off));

  __shared__ float red[8];
  if (lane == 0) red[w] = m;
  __syncthreads();
  m = fmaxf(fmaxf(red[0], red[1]), fmaxf(red[2], red[3]));

  float e[8], sum = 0.f;
#pragma unroll
  for (int j = 0; j < 8; ++j) { e[j] = __expf(f[j] - m); sum += e[j]; }
#pragma unroll
  for (int off = 32; off > 0; off >>= 1) sum += __shfl_xor(sum, off);
  if (lane == 0) red[4 + w] = sum;
  __syncthreads();
  sum = red[4] + red[5] + red[6] + red[7];

  const float inv = 1.f / sum;
  bf16x8 o;
#pragma unroll
  for (int j = 0; j < 8; ++j) o[j] = (bf16_t)(e[j] * inv);
  outp[t] = o;
}

// ---------------------------------------------------------------------------
extern "C" void kernel_launch(void* const* d_in, const int* in_sizes, int n_in,
                              void* d_out, int out_size, void* d_ws, size_t ws_size,
                              hipStream_t stream) {
  const int E = 1024, S = 2048, B = 4;
  const int BS = B * S;  // 8192

  const float* x  = (const float*)d_in[0];
  const float* Wq = (const float*)d_in[1];
  const float* bq = (const float*)d_in[2];
  const float* Wk = (const float*)d_in[3];
  const float* bk = (const float*)d_in[4];
  const float* Wv = (const float*)d_in[5];
  const float* bv = (const float*)d_in[6];
  const float* Wo = (const float*)d_in[7];
  const float* bo = (const float*)d_in[8];
  float* out = (float*)d_out;

  char* w = (char*)d_ws;
  const size_t MB = 1ull << 20;
  bf16_t* Wqkvb = (bf16_t*)(w + 0 * MB);          // 6 MB  [3072,1024]
  bf16_t* Wob   = Wqkvb + 3 * E * E;              // 2 MB
  bf16_t* xb    = (bf16_t*)(w + 8 * MB);          // 16 MB [8192,1024]
  bf16_t* QKVb  = (bf16_t*)(w + 24 * MB);         // 48 MB [8192,3072]
  bf16_t* VTb   = (bf16_t*)(w + 72 * MB);         // 16 MB [B][1024,2048]
  bf16_t* Sb    = (bf16_t*)(w + 88 * MB);         // 32 MB scores
  bf16_t* Pb    = (bf16_t*)(w + 8 * MB);          // 32 MB (xb + QKV[0:16MB] dead)
  bf16_t* Ob    = (bf16_t*)(w + 40 * MB);         // 16 MB (QKV[16:32MB] dead)

  // ---- all casts in one dispatch
  {
    const int totalBlocks = ((4 << 18) + (1 << 21)) / 256;  // 12288
    cast_all<<<totalBlocks, 256, 0, stream>>>(
        (const float4*)Wq, (const float4*)Wk, (const float4*)Wv,
        (const float4*)Wo, (const float4*)x, (bf16x4*)Wqkvb, (bf16x4*)xb);
  }

  // ---- fused QKV projection: [8192,3072] = xb . Wqkv^T + (bq|bk|bv)
  gemm_bt<bf16_t, 3><<<dim3(3 * E / BN, BS / BM, 1), 256, 0, stream>>>(
      xb, Wqkvb, QKVb, bq, bk, bv,
      BS, 3 * E, E, E, E, 3 * E, 1.f, 0, 0, 0);

  // ---- V^T per batch: [2048,1024](ld 3072) -> [1024,2048]
  transpose_bf16<<<dim3(E / 32, S / 32, B), dim3(32, 8), 0, stream>>>(
      QKVb + 2 * E, VTb, S, E, 3 * E, (long long)S * 3 * E, (long long)E * S);

  // ---- scores = Q . K^T * E^-0.5 per batch
  gemm_bt<bf16_t, 0><<<dim3(S / BN, S / BM, B), 256, 0, stream>>>(
      QKVb, QKVb + E, Sb, nullptr, nullptr, nullptr,
      S, S, E, 3 * E, 3 * E, S, 0.03125f,
      (long long)S * 3 * E, (long long)S * 3 * E, (long long)S * S);

  // ---- softmax
  softmax_rows<<<BS, 256, 0, stream>>>(Sb, Pb, S);

  // ---- O = P . (V^T)^T per batch
  gemm_bt<bf16_t, 0><<<dim3(E / BN, S / BM, B), 256, 0, stream>>>(
      Pb, VTb, Ob, nullptr, nullptr, nullptr,
      S, E, S, S, S, E, 1.f,
      (long long)S * S, (long long)E * S, (long long)S * E);

  // ---- y = O . Wo^T + bo
  gemm_bt<float, 1><<<dim3(E / BN, BS / BM, 1), 256, 0, stream>>>(
      Ob, Wob, out, bo, nullptr, nullptr,
      BS, E, E, E, E, E, 1.f, 0, 0, 0);
}